// Round 3
// baseline (2896.227 us; speedup 1.0000x reference)
//
#include <hip/hip_runtime.h>
#include <math.h>

// Problem constants (fixed by reference)
#define NNODES 100000
#define NEDGE  3200000
#define NF     512
#define NH     256
#define NC     40
#define NLAY   8
#define EPSV   1e-5f

// CSR bucket sort parameters
#define NBUK 782          // ceil(NNODES / 128); bucket = dst >> 7
#define EPB  16384        // edges per k_binA/k_histbuk block (1024 thr x 16)
#define BCAP 6144         // k_binB LDS capacity (avg bucket = 4096, sd ~64)

typedef __attribute__((ext_vector_type(8))) short short8;   // 8 bf16 (4 VGPRs)
typedef __attribute__((ext_vector_type(4))) float floatx4;  // MFMA acc

// Feature permutation (epilogue-natural uint8 store order):
//   pos(col) = (col&0xC0) | ((col&15)<<2) | ((col>>4)&3)
//   col(pos) = (pos&0xC0) | ((pos&3)<<4) | ((pos>>2)&15)
// All u8 h-buffers, sup, and Mpack k-rows live in pos space; layer-8 output and
// logits use natural order.

// ---------------------------------------------------------------- utilities

__device__ __forceinline__ float block_sum_256(float v) {
    __shared__ float sb[8];
    #pragma unroll
    for (int off = 32; off; off >>= 1) v += __shfl_down(v, off, 64);
    if ((threadIdx.x & 63) == 0) sb[threadIdx.x >> 6] = v;
    __syncthreads();
    return sb[0] + sb[1] + sb[2] + sb[3];
}

// round-to-nearest-even f32 -> bf16
__device__ __forceinline__ unsigned short bf16_rte(float a) {
    unsigned int u = __float_as_uint(a);
    return (unsigned short)((u + 0x7fffu + ((u >> 16) & 1u)) >> 16);
}
__device__ __forceinline__ unsigned int pack_bf2(float a, float b) {
    unsigned int ua = __float_as_uint(a), ub = __float_as_uint(b);
    ua = (ua + 0x7fffu + ((ua >> 16) & 1u)) >> 16;
    ub = (ub + 0x7fffu + ((ub >> 16) & 1u)) & 0xffff0000u;
    return ua | ub;
}

// ---------------------------------------------------------------- CSR build
// Bucket-only global hist (LDS-aggregated) + two-phase bucket sort. Per-node
// counts/rstart fall out of k_binB's LDS counting sort for free.

__global__ __launch_bounds__(1024) void k_histbuk(const int* __restrict__ dst,
                                                  int* __restrict__ bcnt) {
    __shared__ int lh[NBUK];
    const int t = threadIdx.x;
    if (t < NBUK) lh[t] = 0;
    __syncthreads();
    const int e0 = blockIdx.x * EPB;
    #pragma unroll
    for (int i = 0; i < 16; i++) {
        int e = e0 + i * 1024 + t;          // coalesced across the block
        if (e < NEDGE) atomicAdd(&lh[dst[e] >> 7], 1);
    }
    __syncthreads();
    if (t < NBUK) {
        int c = lh[t];
        if (c) atomicAdd(&bcnt[t], c);      // one global atomic per (block,bucket)
    }
}

// Single-block exclusive scan of 782 bucket counts -> bstart[0..NBUK]; init gcur.
__global__ __launch_bounds__(1024) void k_scanbuk(const int* __restrict__ bcnt,
                                                  int* __restrict__ bstart,
                                                  int* __restrict__ gcur) {
    __shared__ int s[1024];
    const int t = threadIdx.x;
    int v = (t < NBUK) ? bcnt[t] : 0;
    s[t] = v; __syncthreads();
    for (int off = 1; off < 1024; off <<= 1) {
        int u = (t >= off) ? s[t - off] : 0;
        __syncthreads();
        s[t] += u;
        __syncthreads();
    }
    if (t < NBUK) {
        int e = s[t] - v;                   // exclusive
        bstart[t] = e;
        gcur[t] = e;                        // stage cursor starts at bucket base
    }
    if (t == NBUK - 1) bstart[NBUK] = s[t]; // inclusive total == NEDGE
}

// Phase A: bin edges into 782 coarse buckets (128 dst-nodes each).
// One atomic reservation per (block,bucket); run writes stay XCD-local so L2
// merges them into full lines.
// Stage record: {pk = (src:17 | w_e8m7:15), dst_local (7 bits)}
__global__ __launch_bounds__(1024) void k_binA(const int* __restrict__ src,
                                               const int* __restrict__ dst,
                                               const float* __restrict__ w,
                                               int* __restrict__ gcur,
                                               uint2* __restrict__ gstage) {
    __shared__ int lhist[1024];        // per-bucket counts (782 used)
    __shared__ int lrun[NBUK];         // global run base per bucket
    __shared__ int lcnt[NBUK];         // local placement cursor
    const int t = threadIdx.x;
    lhist[t] = 0;
    if (t < NBUK) lcnt[t] = 0;
    __syncthreads();
    const int e0 = blockIdx.x * EPB;
    unsigned int pk[16]; int bk[16]; int dl[16];
    #pragma unroll
    for (int i = 0; i < 16; i++) {
        int e = e0 + i * 1024 + t;     // coalesced across the block
        bk[i] = -1;
        if (e < NEDGE) {
            int d = dst[e];
            bk[i] = d >> 7; dl[i] = d & 127;
            unsigned int wb = bf16_rte(w[e]) & 0x7FFFu;
            pk[i] = ((unsigned int)src[e] << 15) | wb;
            atomicAdd(&lhist[bk[i]], 1);
        }
    }
    __syncthreads();
    if (t < NBUK) {
        int c = lhist[t];
        if (c > 0) lrun[t] = atomicAdd(&gcur[t], c);   // one atomic per (block,bucket)
    }
    __syncthreads();
    #pragma unroll
    for (int i = 0; i < 16; i++) {
        if (bk[i] >= 0) {
            int p = lrun[bk[i]] + atomicAdd(&lcnt[bk[i]], 1);
            gstage[p] = make_uint2(pk[i], (unsigned int)dl[i]);
        }
    }
}

// Phase B: one block per bucket. LDS counting sort by dst_local (7 bits),
// then fully coalesced store of the final epack segment. Also emits per-node
// counts and rstart (free by-product of the LDS histogram + scan).
__global__ __launch_bounds__(256) void k_binB(const int* __restrict__ bstart,
                                              const uint2* __restrict__ gstage,
                                              unsigned int* __restrict__ epack,
                                              int* __restrict__ rstart,
                                              int* __restrict__ counts) {
    __shared__ unsigned int  spk[BCAP];
    __shared__ unsigned char sdl[BCAP];
    __shared__ unsigned int  lout[BCAP];
    __shared__ int lh[256];
    const int b = blockIdx.x, t = threadIdx.x;
    const int base = bstart[b];
    const int end  = bstart[b + 1];
    const int cnt = end - base;
    lh[t] = 0;
    __syncthreads();
    for (int i = t; i < cnt; i += 256) {
        uint2 e = gstage[base + i];
        spk[i] = e.x;
        int d = (int)(e.y & 127u);
        sdl[i] = (unsigned char)d;
        atomicAdd(&lh[d], 1);
    }
    __syncthreads();
    // exclusive scan over 256 slots (only 0..127 nonzero)
    int v = lh[t];
    for (int off = 1; off < 256; off <<= 1) {
        int u = (t >= off) ? lh[t - off] : 0;
        __syncthreads();
        lh[t] += u;
        __syncthreads();
    }
    int excl = lh[t] - v;
    __syncthreads();
    lh[t] = excl;                      // reuse as placement cursor
    // per-node CSR metadata (coalesced 512B per bucket)
    if (t < 128) {
        int node = (b << 7) + t;
        if (node < NNODES) { rstart[node] = base + excl; counts[node] = v; }
    }
    __syncthreads();
    for (int i = t; i < cnt; i += 256) {
        int p = atomicAdd(&lh[sdl[i]], 1);
        lout[p] = spk[i];
    }
    __syncthreads();
    for (int i = t; i < cnt; i += 256) epack[base + i] = lout[i];   // coalesced
}

// ---------------------------------------------------------------- x -> bf16 (coalesced)

__global__ void k_xbf16(const float* __restrict__ X, unsigned short* __restrict__ Xb, long n8) {
    long i = (long)blockIdx.x * 256 + threadIdx.x;   // one uint4 (8 bf16) per thread
    if (i >= n8) return;
    const float* p = X + i * 8;
    float4 a = *(const float4*)p;
    float4 b = *(const float4*)(p + 4);
    uint4 o;
    o.x = pack_bf2(a.x, a.y); o.y = pack_bf2(a.z, a.w);
    o.z = pack_bf2(b.x, b.y); o.w = pack_bf2(b.z, b.w);
    *(uint4*)(Xb + i * 8) = o;
}

// ---------------------------------------------------------------- ortho prep

__global__ void k_zc0(const float* __restrict__ W0, float* __restrict__ Zc0) {
    int r = blockIdx.x, t = threadIdx.x;
    float a = W0[r * NF + t];
    float b = W0[r * NF + 256 + t];
    float mean = block_sum_256(a + b) * (1.0f / 512.0f);
    Zc0[r * NF + t]       = a - mean;
    Zc0[r * NF + 256 + t] = b - mean;
}

__global__ void k_zcC(const float* __restrict__ convW, float* __restrict__ ZcC) {
    int g = blockIdx.x >> 8, r = blockIdx.x & 255, t = threadIdx.x;
    float v = 0.5f * convW[((size_t)g * NH + r) * NH + t] + ((r == t) ? 0.5f : 0.0f);
    float mean = block_sum_256(v) * (1.0f / 256.0f);
    ZcC[((size_t)g * NH + r) * NH + t] = v - mean;
}

// S[b] = Zc[b] @ Zc[b]^T + EPS*I   (b=0: Zc0 K=512; b>0: ZcC[b-1] K=256)
__global__ __launch_bounds__(256) void k_gram(const float* __restrict__ Zc0,
                                              const float* __restrict__ ZcC,
                                              float* __restrict__ S) {
    const int b = blockIdx.z;
    const float* A = (b == 0) ? Zc0 : (ZcC + (size_t)(b - 1) * 65536);
    const int K = (b == 0) ? 512 : 256;
    const int r0 = blockIdx.y * 64, c0 = blockIdx.x * 64;
    __shared__ float As[32][76], Bs[32][76];
    const int t = threadIdx.x, tx = t & 15, ty = t >> 4;
    const int lr = t >> 2, lk = (t & 3) * 4;
    float acc[4][4] = {};
    for (int k0 = 0; k0 < K; k0 += 32) {
        float4 a0 = *(const float4*)(A + (size_t)(r0 + lr) * K + k0 + lk);
        float4 a1 = *(const float4*)(A + (size_t)(r0 + lr) * K + k0 + lk + 16);
        As[lk + 0][lr] = a0.x; As[lk + 1][lr] = a0.y; As[lk + 2][lr] = a0.z; As[lk + 3][lr] = a0.w;
        As[lk + 16][lr] = a1.x; As[lk + 17][lr] = a1.y; As[lk + 18][lr] = a1.z; As[lk + 19][lr] = a1.w;
        float4 b0 = *(const float4*)(A + (size_t)(c0 + lr) * K + k0 + lk);
        float4 b1 = *(const float4*)(A + (size_t)(c0 + lr) * K + k0 + lk + 16);
        Bs[lk + 0][lr] = b0.x; Bs[lk + 1][lr] = b0.y; Bs[lk + 2][lr] = b0.z; Bs[lk + 3][lr] = b0.w;
        Bs[lk + 16][lr] = b1.x; Bs[lk + 17][lr] = b1.y; Bs[lk + 18][lr] = b1.z; Bs[lk + 19][lr] = b1.w;
        __syncthreads();
        #pragma unroll
        for (int kk = 0; kk < 32; kk++) {
            float a[4], bb[4];
            *(float4*)&a[0]  = *(const float4*)&As[kk][ty * 4];
            *(float4*)&bb[0] = *(const float4*)&Bs[kk][tx * 4];
            #pragma unroll
            for (int i = 0; i < 4; i++)
                #pragma unroll
                for (int j = 0; j < 4; j++) acc[i][j] = fmaf(a[i], bb[j], acc[i][j]);
        }
        __syncthreads();
    }
    #pragma unroll
    for (int i = 0; i < 4; i++)
        #pragma unroll
        for (int j = 0; j < 4; j++) {
            int r = r0 + ty * 4 + i, c = c0 + tx * 4 + j;
            float v = acc[i][j];
            if (r == c) v += EPSV;
            S[(size_t)b * 65536 + r * NH + c] = v;
        }
}

__global__ void k_fro(const float* __restrict__ S, float* __restrict__ scales) {
    __shared__ float sb[8];
    const int b = blockIdx.x, t = threadIdx.x;
    const float* p = S + (size_t)b * 65536;
    float s = 0.f;
    for (int i = t; i < 65536; i += 256) { float v = p[i]; s = fmaf(v, v, s); }
    #pragma unroll
    for (int off = 32; off; off >>= 1) s += __shfl_down(s, off, 64);
    if ((t & 63) == 0) sb[t >> 6] = s;
    __syncthreads();
    if (t == 0) {
        float nrm = sqrtf(sb[0] + sb[1] + sb[2] + sb[3]);
        scales[b]      = 1.0f / nrm;
        scales[16 + b] = rsqrtf(nrm);
    }
}

// B1 = 1.5*I - 0.5*invn*S  (closed-form first Newton-Schulz iteration)
__global__ void k_initB1(const float* __restrict__ S, const float* __restrict__ scales,
                         float* __restrict__ B) {
    int i = blockIdx.x * 256 + threadIdx.x;     // 9*65536
    int b = i >> 16, m = i & 65535;
    float v = -0.5f * scales[b] * S[i];
    if ((m >> 8) == (m & 255)) v += 1.5f;
    B[i] = v;
}

// Batch-18: b<9 -> T1[b] = B[b]@B[b] ; b>=9 -> T2[b-9] = B[b-9]@S[b-9]
__global__ __launch_bounds__(256) void k_ns_pair(const float* __restrict__ Bb,
                                                 const float* __restrict__ Smat,
                                                 float* __restrict__ T1b,
                                                 float* __restrict__ T2b) {
    const int b = blockIdx.z;
    const int bb = (b < 9) ? b : b - 9;
    const float* A  = Bb + (size_t)bb * 65536;
    const float* Bm = (b < 9) ? A : (Smat + (size_t)bb * 65536);
    float* C = (b < 9) ? (T1b + (size_t)bb * 65536) : (T2b + (size_t)bb * 65536);
    const int r0 = blockIdx.y * 64, c0 = blockIdx.x * 64;
    __shared__ float As[32][76], Bs[32][76];
    const int t = threadIdx.x, tx = t & 15, ty = t >> 4;
    const int lr = t >> 2, lk = (t & 3) * 4;
    const int bk = t >> 3, bc = (t & 7) * 8;
    float acc[4][4] = {};
    for (int k0 = 0; k0 < 256; k0 += 32) {
        float4 a0 = *(const float4*)(A + (size_t)(r0 + lr) * 256 + k0 + lk);
        float4 a1 = *(const float4*)(A + (size_t)(r0 + lr) * 256 + k0 + lk + 16);
        As[lk + 0][lr] = a0.x; As[lk + 1][lr] = a0.y; As[lk + 2][lr] = a0.z; As[lk + 3][lr] = a0.w;
        As[lk + 16][lr] = a1.x; As[lk + 17][lr] = a1.y; As[lk + 18][lr] = a1.z; As[lk + 19][lr] = a1.w;
        float4 b0 = *(const float4*)(Bm + (size_t)(k0 + bk) * 256 + c0 + bc);
        float4 b1 = *(const float4*)(Bm + (size_t)(k0 + bk) * 256 + c0 + bc + 4);
        *(float4*)&Bs[bk][bc]     = b0;
        *(float4*)&Bs[bk][bc + 4] = b1;
        __syncthreads();
        #pragma unroll
        for (int kk = 0; kk < 32; kk++) {
            float a[4], bb2[4];
            *(float4*)&a[0]   = *(const float4*)&As[kk][ty * 4];
            *(float4*)&bb2[0] = *(const float4*)&Bs[kk][tx * 4];
            #pragma unroll
            for (int i = 0; i < 4; i++)
                #pragma unroll
                for (int j = 0; j < 4; j++) acc[i][j] = fmaf(a[i], bb2[j], acc[i][j]);
        }
        __syncthreads();
    }
    #pragma unroll
    for (int i = 0; i < 4; i++)
        #pragma unroll
        for (int j = 0; j < 4; j++)
            C[(size_t)(r0 + ty * 4 + i) * 256 + c0 + tx * 4 + j] = acc[i][j];
}

// Batched small NN matmul, M=256, tile 64x64, Ktile 32.
// mode 1: C = 1.5*C - 0.5*scale[b]*(A@B) ; mode 2: C = scale[b]*(A@B)
__global__ __launch_bounds__(256) void k_small_nn(const float* __restrict__ A0,
                                                  const float* __restrict__ B0,
                                                  float* __restrict__ C0,
                                                  int sA, int sB, int sC,
                                                  int K, int Ncols, int mode,
                                                  const float* __restrict__ scale) {
    const int b = blockIdx.z;
    const float* A = A0 + (size_t)b * sA;
    const float* Bm = B0 + (size_t)b * sB;
    float* C = C0 + (size_t)b * sC;
    const int r0 = blockIdx.y * 64, c0 = blockIdx.x * 64;
    __shared__ float As[32][76], Bs[32][76];
    const int t = threadIdx.x, tx = t & 15, ty = t >> 4;
    const int lr = t >> 2, lk = (t & 3) * 4;
    const int bk = t >> 3, bc = (t & 7) * 8;
    float acc[4][4] = {};
    for (int k0 = 0; k0 < K; k0 += 32) {
        float4 a0 = *(const float4*)(A + (size_t)(r0 + lr) * K + k0 + lk);
        float4 a1 = *(const float4*)(A + (size_t)(r0 + lr) * K + k0 + lk + 16);
        As[lk + 0][lr] = a0.x; As[lk + 1][lr] = a0.y; As[lk + 2][lr] = a0.z; As[lk + 3][lr] = a0.w;
        As[lk + 16][lr] = a1.x; As[lk + 17][lr] = a1.y; As[lk + 18][lr] = a1.z; As[lk + 19][lr] = a1.w;
        float4 b0 = *(const float4*)(Bm + (size_t)(k0 + bk) * Ncols + c0 + bc);
        float4 b1 = *(const float4*)(Bm + (size_t)(k0 + bk) * Ncols + c0 + bc + 4);
        *(float4*)&Bs[bk][bc]     = b0;
        *(float4*)&Bs[bk][bc + 4] = b1;
        __syncthreads();
        #pragma unroll
        for (int kk = 0; kk < 32; kk++) {
            float a[4], bb[4];
            *(float4*)&a[0]  = *(const float4*)&As[kk][ty * 4];
            *(float4*)&bb[0] = *(const float4*)&Bs[kk][tx * 4];
            #pragma unroll
            for (int i = 0; i < 4; i++)
                #pragma unroll
                for (int j = 0; j < 4; j++) acc[i][j] = fmaf(a[i], bb[j], acc[i][j]);
        }
        __syncthreads();
    }
    #pragma unroll
    for (int i = 0; i < 4; i++)
        #pragma unroll
        for (int j = 0; j < 4; j++) {
            size_t idx = (size_t)(r0 + ty * 4 + i) * Ncols + c0 + tx * 4 + j;
            if (mode == 1) C[idx] = 1.5f * C[idx] - 0.5f * scale[b] * acc[i][j];
            else C[idx] = scale[b] * acc[i][j];
        }
}

// ---------------------------------------------------------------- MFMA B-operand packing
// Fragment layouts (gfx950 mfma_f32_16x16x32_bf16):
//   A: lane holds A[m=lane&15][k=(lane>>4)*8 + j], j=0..7
//   B: lane holds B[k=(lane>>4)*8 + j][n=lane&15]
//   C/D: col=lane&15, row=(lane>>4)*4 + reg
// Pack layout: [c=K/64][s=2][tg=16][lane=64][j=8] bf16 (per-chunk 32 KB contiguous)

// Mpack k-index is in pos space: Mpack[k_pos][n] = M[col(k_pos)][n]
__global__ void k_prepM(const float* __restrict__ tbuf, unsigned short* __restrict__ Mpack) {
    int idx = blockIdx.x * 256 + threadIdx.x;
    int lane = idx & 63;
    int tg   = (idx >> 6) & 15;
    int s    = (idx >> 10) & 1;
    int c    = (idx >> 11) & 3;
    int l    = idx >> 13;
    float theta = logf(0.5f / (float)(l + 1) + 1.0f);
    float mtheta = 1.0f - theta;
    int n  = tg * 16 + (lane & 15);
    int k0 = c * 64 + s * 32 + (lane >> 4) * 8;
    const float* T = tbuf + (size_t)l * 65536;
    unsigned short o[8];
    #pragma unroll
    for (int j = 0; j < 8; j++) {
        int kp = k0 + j;
        int kn = (kp & 0xC0) | ((kp & 3) << 4) | ((kp >> 2) & 15);   // col(pos)
        float v = theta * T[(size_t)kn * 256 + n] + ((kn == n) ? mtheta : 0.0f);
        o[j] = bf16_rte(v);
    }
    *(uint4*)(Mpack + (size_t)idx * 8) = *(uint4*)o;
}

// fc0 k-space = x features (natural, no perm)
__global__ void k_prepW0(const float* __restrict__ W0o, unsigned short* __restrict__ Wpack) {
    int idx = blockIdx.x * 256 + threadIdx.x;
    int lane = idx & 63;
    int tg   = (idx >> 6) & 15;
    int s    = (idx >> 10) & 1;
    int c    = idx >> 11;                    // 0..7
    int n  = tg * 16 + (lane & 15);
    int k0 = c * 64 + s * 32 + (lane >> 4) * 8;
    const float* p = W0o + (size_t)n * NF + k0;
    unsigned short o[8];
    #pragma unroll
    for (int j = 0; j < 8; j++) o[j] = bf16_rte(p[j]);
    *(uint4*)(Wpack + (size_t)idx * 8) = *(uint4*)o;
}

// ---------------------------------------------------------------- fc0 (MFMA, LDS-free)

// h0u8/h0scale = quant(relu(xbf @ W0o^T + b0)). K=512 (8 chunks).
__global__ __launch_bounds__(256) void k_fc0_mfma(const unsigned short* __restrict__ Xb,
                                                  const unsigned short* __restrict__ Wp,
                                                  const float* __restrict__ bias,
                                                  unsigned char* __restrict__ h0u8,
                                                  float* __restrict__ h0scale) {
    __shared__ int rmax[64];
    const int t = threadIdx.x, lane = t & 63, w = t >> 6;
    const int q = lane >> 4, m = lane & 15;
    const int r0 = blockIdx.x * 64;
    if (t < 64) rmax[t] = 0;
    floatx4 acc[4][4] = {};
    #pragma unroll
    for (int c = 0; c < 8; c++) {
        #pragma unroll
        for (int s = 0; s < 2; s++) {
            short8 afr[4];
            #pragma unroll
            for (int i = 0; i < 4; i++) {
                int row = r0 + i * 16 + m; if (row > NNODES - 1) row = NNODES - 1;
                afr[i] = *(const short8*)(Xb + (size_t)row * NF + c * 64 + s * 32 + q * 8);
            }
            #pragma unroll
            for (int tg = 0; tg < 4; tg++) {
                short8 bfr = *(const short8*)(Wp + (size_t)c * 16384 + s * 8192
                                              + (w * 4 + tg) * 512 + lane * 8);
                #pragma unroll
                for (int i = 0; i < 4; i++)
                    acc[i][tg] = __builtin_amdgcn_mfma_f32_16x16x32_bf16(afr[i], bfr, acc[i][tg], 0, 0, 0);
            }
        }
    }
    // bias + relu in place
    #pragma unroll
    for (int tg = 0; tg < 4; tg++) {
        float bv = bias[w * 64 + tg * 16 + m];
        #pragma unroll
        for (int i = 0; i < 4; i++)
            #pragma unroll
            for (int r = 0; r < 4; r++)
                acc[i][tg][r] = fmaxf(acc[i][tg][r] + bv, 0.f);
    }
    __syncthreads();   // rmax init visible
    // row max (phase A)
    #pragma unroll
    for (int i = 0; i < 4; i++)
        #pragma unroll
        for (int r = 0; r < 4; r++) {
            float mx = fmaxf(fmaxf(acc[i][0][r], acc[i][1][r]),
                             fmaxf(acc[i][2][r], acc[i][3][r]));
            mx = fmaxf(mx, __shfl_xor(mx, 1));
            mx = fmaxf(mx, __shfl_xor(mx, 2));
            mx = fmaxf(mx, __shfl_xor(mx, 4));
            mx = fmaxf(mx, __shfl_xor(mx, 8));
            if (m == 0) atomicMax(&rmax[i * 16 + q * 4 + r], __float_as_int(mx));
        }
    __syncthreads();
    // quantize + store (phase B)
    #pragma unroll
    for (int i = 0; i < 4; i++)
        #pragma unroll
        for (int r = 0; r < 4; r++) {
            int row = r0 + i * 16 + q * 4 + r;
            if (row >= NNODES) continue;
            float rm = __int_as_float(rmax[i * 16 + q * 4 + r]);
            float qs = rm > 0.f ? 255.0f / rm : 0.f;
            unsigned int b0 = (unsigned int)fmaf(acc[i][0][r], qs, 0.5f);
            unsigned int b1 = (unsigned int)fmaf(acc[i][1][r], qs, 0.5f);
            unsigned int b2 = (unsigned int)fmaf(acc[i][2][r], qs, 0.5f);
            unsigned int b3 = (unsigned int)fmaf(acc[i][3][r], qs, 0.5f);
            *(unsigned int*)(h0u8 + (size_t)row * NH + w * 64 + m * 4) =
                b0 | (b1 << 8) | (b2 << 16) | (b3 << 24);
        }
    if (t < 64 && r0 + t < NNODES)
        h0scale[r0 + t] = __int_as_float(rmax[t]) * (1.0f / 255.0f);
}

// ---------------------------------------------------------------- fused layer
// Per block: 64 output rows. Phase 1 (gather): wave w computes sup rows
// w*16..w*16+15 (identical inner loop to the old k_spmm), writing bf16 to a
// 32 KB XOR-swizzled LDS tile instead of global supbf — kills the 51.2 MB
// write + 51.2 MB read per layer and lets gather VALU overlap other blocks'
// MFMA on the same CU (separate pipes). Phase 2: MFMA epilogue identical to
// the old k_gemm_layer, A-fragments from LDS.
// Swizzle: byte ^= ((row&7)<<4). Write side (64 lanes x 8B, one row): 4/bank
// (minimum). Read side (ds_read_b128): each 16B slot hit by exactly 8 lanes
// = 256/32 bank minimum -> conflict-free.
__global__ __launch_bounds__(256) void k_layer(const int* __restrict__ rstart,
                                               const int* __restrict__ counts,
                                               const unsigned int* __restrict__ epack,
                                               const unsigned char* __restrict__ hu8,
                                               const float* __restrict__ hscale,
                                               const unsigned char* __restrict__ h0u8,
                                               const float* __restrict__ h0scale,
                                               const unsigned short* __restrict__ Mp,
                                               unsigned char* __restrict__ out_u8,
                                               float* __restrict__ out_scale,
                                               unsigned short* __restrict__ out_bf) {
    __shared__ unsigned char sup[64 * 512];   // bf16[64][256] pos-space, swizzled
    __shared__ int2 se[4][64];
    __shared__ int rmax[64];
    const int t = threadIdx.x, lane = t & 63, w = t >> 6;
    const int r0 = blockIdx.x * 64;
    if (t < 64) rmax[t] = 0;

    // ---- phase 1: gather (wave w owns rows w*16 .. w*16+15)
    for (int nl0 = 0; nl0 < 16; nl0++) {
        const int nl = w * 16 + nl0;
        const int node = r0 + nl;
        float o0 = 0.f, o1 = 0.f, o2 = 0.f, o3 = 0.f;
        if (node < NNODES) {
            const int start = rstart[node], deg = counts[node];
            for (int base = 0; base < deg; base += 64) {
                int j = base + lane;
                if (j < deg) {
                    unsigned int u = epack[start + j];
                    int s = (int)(u >> 15);
                    float wt = __uint_as_float((u & 0x7FFFu) << 16);   // e8m7, sign 0
                    se[w][lane] = make_int2(s, __float_as_int(wt * hscale[s] * 0.9f));
                }
                int mm = deg - base; if (mm > 64) mm = 64;
                int e = 0;
                for (; e + 8 <= mm; e += 8) {
                    float ww[8]; unsigned int g[8];
                    #pragma unroll
                    for (int u2 = 0; u2 < 8; u2++) {
                        int2 ed = se[w][e + u2];
                        ww[u2] = __int_as_float(ed.y);
                        g[u2] = *(const unsigned int*)(hu8 + ((size_t)ed.x << 8) + (lane << 2));
                    }
                    #pragma unroll
                    for (int u2 = 0; u2 < 8; u2++) {
                        o0 = fmaf(ww[u2], (float)(g[u2] & 0xFFu), o0);
                        o1 = fmaf(ww[u2], (float)((g[u2] >> 8) & 0xFFu), o1);
                        o2 = fmaf(ww[u2], (float)((g[u2] >> 16) & 0xFFu), o2);
                        o3 = fmaf(ww[u2], (float)(g[u2] >> 24), o3);
                    }
                }
                for (; e < mm; e++) {
                    int2 ed = se[w][e];
                    float ww = __int_as_float(ed.y);
                    unsigned int g = *(const unsigned int*)(hu8 + ((size_t)ed.x << 8) + (lane << 2));
                    o0 = fmaf(ww, (float)(g & 0xFFu), o0);
                    o1 = fmaf(ww, (float)((g >> 8) & 0xFFu), o1);
                    o2 = fmaf(ww, (float)((g >> 16) & 0xFFu), o2);
                    o3 = fmaf(ww, (float)(g >> 24), o3);
                }
            }
            unsigned int rg = *(const unsigned int*)(h0u8 + ((size_t)node << 8) + (lane << 2));
            float rs = h0scale[node] * 0.1f;
            o0 = fmaf(rs, (float)(rg & 0xFFu), o0);
            o1 = fmaf(rs, (float)((rg >> 8) & 0xFFu), o1);
            o2 = fmaf(rs, (float)((rg >> 16) & 0xFFu), o2);
            o3 = fmaf(rs, (float)(rg >> 24), o3);
        }
        uint2 ov;
        ov.x = pack_bf2(o0, o1);
        ov.y = pack_bf2(o2, o3);
        *(uint2*)&sup[nl * 512 + ((lane * 8) ^ ((nl & 7) << 4))] = ov;
    }
    __syncthreads();

    // ---- phase 2: MFMA (A from swizzled LDS, B from L2-resident Mp)
    const int q = lane >> 4, m = lane & 15;
    floatx4 acc[4][4] = {};
    #pragma unroll
    for (int c = 0; c < 4; c++) {
        #pragma unroll
        for (int s = 0; s < 2; s++) {
            short8 afr[4];
            #pragma unroll
            for (int i = 0; i < 4; i++) {
                int rl = i * 16 + m;
                afr[i] = *(const short8*)&sup[rl * 512
                           + ((c * 128 + s * 64 + q * 16) ^ ((rl & 7) << 4))];
            }
            #pragma unroll
            for (int tg = 0; tg < 4; tg++) {
                short8 bfr = *(const short8*)(Mp + (size_t)c * 16384 + s * 8192
                                              + (w * 4 + tg) * 512 + lane * 8);
                #pragma unroll
                for (int i = 0; i < 4; i++)
                    acc[i][tg] = __builtin_amdgcn_mfma_f32_16x16x32_bf16(afr[i], bfr, acc[i][tg], 0, 0, 0);
            }
        }
    }
    // relu in place
    #pragma unroll
    for (int i = 0; i < 4; i++)
        #pragma unroll
        for (int tg = 0; tg < 4; tg++)
            #pragma unroll
            for (int r = 0; r < 4; r++)
                acc[i][tg][r] = fmaxf(acc[i][tg][r], 0.f);

    if (out_bf) {   // layer 8: natural bf16 scatter
        #pragma unroll
        for (int i = 0; i < 4; i++)
            #pragma unroll
            for (int tg = 0; tg < 4; tg++) {
                int col = w * 64 + tg * 16 + m;
                #pragma unroll
                for (int r = 0; r < 4; r++) {
                    int row = r0 + i * 16 + q * 4 + r;
                    if (row >= NNODES) continue;
                    out_bf[(size_t)row * NH + col] = bf16_rte(acc[i][tg][r]);
                }
            }
        return;
    }
    // phase A: row max (rmax init visible via post-gather barrier)
    #pragma unroll
    for (int i = 0; i < 4; i++)
        #pragma unroll
        for (int r = 0; r < 4; r++) {
            float mx = fmaxf(fmaxf(acc[i][0][r], acc[i][1][r]),
                             fmaxf(acc[i][2][r], acc[i][3][r]));
            mx = fmaxf(mx, __shfl_xor(mx, 1));
            mx = fmaxf(mx, __shfl_xor(mx, 2));
            mx = fmaxf(mx, __shfl_xor(mx, 4));
            mx = fmaxf(mx, __shfl_xor(mx, 8));
            if (m == 0) atomicMax(&rmax[i * 16 + q * 4 + r], __float_as_int(mx));
        }
    __syncthreads();
    // phase B: quantize + pos-space dword stores
    #pragma unroll
    for (int i = 0; i < 4; i++)
        #pragma unroll
        for (int r = 0; r < 4; r++) {
            int row = r0 + i * 16 + q * 4 + r;
            if (row >= NNODES) continue;
            float rm = __int_as_float(rmax[i * 16 + q * 4 + r]);
            float qs = rm > 0.f ? 255.0f / rm : 0.f;
            unsigned int b0 = (unsigned int)fmaf(acc[i][0][r], qs, 0.5f);
            unsigned int b1 = (unsigned int)fmaf(acc[i][1][r], qs, 0.5f);
            unsigned int b2 = (unsigned int)fmaf(acc[i][2][r], qs, 0.5f);
            unsigned int b3 = (unsigned int)fmaf(acc[i][3][r], qs, 0.5f);
            *(unsigned int*)(out_u8 + (size_t)row * NH + w * 64 + m * 4) =
                b0 | (b1 << 8) | (b2 << 16) | (b3 << 24);
        }
    if (t < 64 && r0 + t < NNODES)
        out_scale[r0 + t] = __int_as_float(rmax[t]) * (1.0f / 255.0f);
}

// ---------------------------------------------------------------- logits + log_softmax (bf16 h, natural)

__global__ __launch_bounds__(256) void k_logits(const unsigned short* __restrict__ hb,
                                                const float* __restrict__ W1,
                                                const float* __restrict__ b1,
                                                float* __restrict__ out, int nrows) {
    __shared__ float hs[32][260];
    __shared__ float Ws[40][260];
    __shared__ float ls[32][44];
    __shared__ float lse[32];
    const int t = threadIdx.x;
    const int row0 = blockIdx.x * 32;
    for (int i = t; i < 40 * 64; i += 256) {
        int c = i >> 6, k4 = i & 63;
        *(float4*)&Ws[c][k4 * 4] = *(const float4*)(W1 + (size_t)c * NH + k4 * 4);
    }
    for (int i = t; i < 32 * 32; i += 256) {
        int r = i >> 5, k8 = i & 31;
        int gr = row0 + r;
        uint4 v = make_uint4(0u, 0u, 0u, 0u);
        if (gr < nrows) v = *(const uint4*)(hb + ((size_t)gr << 8) + k8 * 8);
        float* d = &hs[r][k8 * 8];
        d[0] = __uint_as_float(v.x << 16); d[1] = __uint_as_float(v.x & 0xffff0000u);
        d[2] = __uint_as_float(v.y << 16); d[3] = __uint_as_float(v.y & 0xffff0000u);
        d[4] = __uint_as_float(v.z << 16); d[5] = __uint_as_float(v.z & 0xffff0000u);
        d[6] = __uint_as_float(v.w << 16); d[7] = __uint_as_float(v.w & 0xffff0000u);
    }
    __syncthreads();
    const int r = t & 31, cg = t >> 5;   // cg in 0..7, 5 classes each
    float acc[5];
    #pragma unroll
    for (int j = 0; j < 5; j++) acc[j] = b1[cg * 5 + j];
    for (int k = 0; k < NH; k++) {
        float hv = hs[r][k];
        #pragma unroll
        for (int j = 0; j < 5; j++) acc[j] = fmaf(hv, Ws[cg * 5 + j][k], acc[j]);
    }
    #pragma unroll
    for (int j = 0; j < 5; j++) ls[r][cg * 5 + j] = acc[j];
    __syncthreads();
    if (t < 32) {
        float m = -3.4e38f;
        for (int c = 0; c < NC; c++) m = fmaxf(m, ls[t][c]);
        float s = 0.f;
        for (int c = 0; c < NC; c++) s += expf(ls[t][c] - m);
        lse[t] = m + logf(s);
    }
    __syncthreads();
    for (int i = t; i < 32 * NC; i += 256) {
        int r2 = i / NC, c = i % NC;
        int gr = row0 + r2;
        if (gr < nrows) out[(size_t)gr * NC + c] = ls[r2][c] - lse[r2];
    }
}

// ---------------------------------------------------------------- launch

extern "C" void kernel_launch(void* const* d_in, const int* in_sizes, int n_in,
                              void* d_out, int out_size, void* d_ws, size_t ws_size,
                              hipStream_t stream) {
    const float* x      = (const float*)d_in[0];
    const int*   e_src  = (const int*)d_in[1];
    const int*   e_dst  = (const int*)d_in[2];
    const float* e_w    = (const float*)d_in[3];
    const float* W0     = (const float*)d_in[4];
    const float* b0     = (const float*)d_in[5];
    const float* convW  = (const float*)d_in[6];
    const float* W1     = (const float*)d_in[7];
    const float* b1     = (const float*)d_in[8];
    float* out = (float*)d_out;

    char* ws = (char*)d_ws;
    const size_t OFF_H0U8   = 0;                                    // u8 [N,256] 25.6 MB
    const size_t OFF_HU8A   = OFF_H0U8 + (size_t)NNODES * NH;       // u8 [N,256]
    const size_t OFF_HU8B   = OFF_HU8A + (size_t)NNODES * NH;       // u8 [N,256]
    const size_t OFF_H0SC   = OFF_HU8B + (size_t)NNODES * NH;       // f32 [N]
    const size_t OFF_SCA    = OFF_H0SC + (size_t)NNODES * 4;
    const size_t OFF_SCB    = OFF_SCA + (size_t)NNODES * 4;
    const size_t OFF_SUPBF  = OFF_SCB + (size_t)NNODES * 4;         // 51.2 MB region (gstage alias, CSR build only)
    const size_t OFF_HBF    = OFF_SUPBF + (size_t)NNODES * NH * 2;  // bf16 [N,256] (layer-8)
    const size_t OFF_XBF    = OFF_HBF + (size_t)NNODES * NH * 2;    // bf16 [N,512] 102.4 MB
    const size_t OFF_EPACK  = OFF_XBF + (size_t)NNODES * NF * 2;    // u32 [E] 12.8 MB
    const size_t OFF_RSTART = OFF_EPACK + (size_t)NEDGE * 4;
    const size_t OFF_COUNTS = OFF_RSTART + (size_t)NNODES * 4;
    const size_t OFF_CURSOR = OFF_COUNTS + (size_t)NNODES * 4;      // gcur (782) + bcnt + bstart
    const size_t OFF_BSUM   = OFF_CURSOR + (size_t)NNODES * 4;
    const size_t OFF_ZC0    = OFF_BSUM + 1024;
    const size_t OFF_ZCC    = OFF_ZC0 + 256 * 512 * 4;
    const size_t OFF_S      = OFF_ZCC + 8 * 65536 * 4;
    const size_t OFF_B      = OFF_S + 9 * 65536 * 4;
    const size_t OFF_T1     = OFF_B + 9 * 65536 * 4;
    const size_t OFF_T2     = OFF_T1 + 9 * 65536 * 4;
    const size_t OFF_T      = OFF_T2 + 9 * 65536 * 4;
    const size_t OFF_W0O    = OFF_T + 8 * 65536 * 4;
    const size_t OFF_SCALES = OFF_W0O + 256 * 512 * 4;
    const size_t OFF_MPACK  = OFF_SCALES + 1024;
    const size_t OFF_WPACK  = OFF_MPACK + 8 * 65536 * 2;

    unsigned char* h0u8 = (unsigned char*)(ws + OFF_H0U8);
    unsigned char* hu8A = (unsigned char*)(ws + OFF_HU8A);
    unsigned char* hu8B = (unsigned char*)(ws + OFF_HU8B);
    float* h0sc = (float*)(ws + OFF_H0SC);
    float* scA  = (float*)(ws + OFF_SCA);
    float* scB  = (float*)(ws + OFF_SCB);
    unsigned short* hbf   = (unsigned short*)(ws + OFF_HBF);
    unsigned short* xbf   = (unsigned short*)(ws + OFF_XBF);
    unsigned int* epack  = (unsigned int*)(ws + OFF_EPACK);
    int*    rstart = (int*)(ws + OFF_RSTART);
    int*    counts = (int*)(ws + OFF_COUNTS);
    int*    gcur   = (int*)(ws + OFF_CURSOR);
    int*    bcnt   = (int*)(ws + OFF_CURSOR + 4096);
    int*    bstart = (int*)(ws + OFF_CURSOR + 8192);                // NBUK+1 ints
    float*  Zc0    = (float*)(ws + OFF_ZC0);
    float*  ZcC    = (float*)(ws + OFF_ZCC);
    float*  Smat   = (float*)(ws + OFF_S);
    float*  Bb     = (float*)(ws + OFF_B);
    float*  T1b    = (float*)(ws + OFF_T1);
    float*  T2b    = (float*)(ws + OFF_T2);
    float*  tbuf   = (float*)(ws + OFF_T);
    float*  W0o    = (float*)(ws + OFF_W0O);
    float*  scales = (float*)(ws + OFF_SCALES);
    unsigned short* Mpack = (unsigned short*)(ws + OFF_MPACK);
    unsigned short* Wpack = (unsigned short*)(ws + OFF_WPACK);
    uint2* gstage = (uint2*)(ws + OFF_SUPBF);   // 25.6 MB alias; dead after CSR build

    (void)in_sizes; (void)n_in; (void)out_size; (void)ws_size;

    // ---- CSR build (bucket-only global hist, then two-phase bucket sort)
    hipMemsetAsync(bcnt, 0, (size_t)NBUK * 4, stream);
    const int NBA = (NEDGE + EPB - 1) / EPB;   // 196
    k_histbuk<<<NBA, 1024, 0, stream>>>(e_dst, bcnt);
    k_scanbuk<<<1, 1024, 0, stream>>>(bcnt, bstart, gcur);
    k_binA<<<NBA, 1024, 0, stream>>>(e_src, e_dst, e_w, gcur, gstage);
    k_binB<<<NBUK, 256, 0, stream>>>(bstart, gstage, epack, rstart, counts);

    // ---- x -> bf16 (coalesced one-shot)
    const long N8 = (long)NNODES * NF / 8;   // 6,400,000
    k_xbf16<<<(int)((N8 + 255) / 256), 256, 0, stream>>>(x, xbf, N8);

    // ---- ortho: batched Newton-Schulz (T=5; first iteration closed-form)
    k_zc0<<<256, 256, 0, stream>>>(W0, Zc0);
    k_zcC<<<8 * 256, 256, 0, stream>>>(convW, ZcC);
    k_gram<<<dim3(4, 4, 9), 256, 0, stream>>>(Zc0, ZcC, Smat);
    k_fro<<<9, 256, 0, stream>>>(Smat, scales);
    k_initB1<<<9 * 256, 256, 0, stream>>>(Smat, scales, Bb);
    for (int it = 1; it < 5; it++) {
        k_ns_pair<<<dim3(4, 4, 18), 256, 0, stream>>>(Bb, Smat, T1b, T2b);
        k_small_nn<<<dim3(4, 4, 9), 256, 0, stream>>>(T1b, T2b, Bb, 65536, 65536, 65536,
                                                      256, 256, 1, scales);
    }
    // W0o = (B0 @ Zc0) * rsqn[0]; t[g] = (B[g+1] @ ZcC[g]) * rsqn[g+1]
    k_small_nn<<<dim3(8, 4, 1), 256, 0, stream>>>(Bb, Zc0, W0o, 0, 0, 0,
                                                  256, 512, 2, scales + 16);
    k_small_nn<<<dim3(4, 4, 8), 256, 0, stream>>>(Bb + 65536, ZcC, tbuf, 65536, 65536, 65536,
                                                  256, 256, 2, scales + 17);

    // ---- pack B-operands for MFMA
    k_prepM<<<256, 256, 0, stream>>>(tbuf, Mpack);
    k_prepW0<<<64, 256, 0, stream>>>(W0o, Wpack);

    // ---- fc0 (MFMA, LDS-free): h0u8/h0sc = quant(relu(xbf @ W0o^T + b0))
    const int GB = (NNODES + 63) / 64;   // 1563
    k_fc0_mfma<<<GB, 256, 0, stream>>>(xbf, Wpack, b0, h0u8, h0sc);

    // ---- 8 GCNII layers: fused u8-gather-SpMM + MFMA GEMM (sup lives in LDS)
    const unsigned char* hin = h0u8;
    const float* hinsc = h0sc;
    unsigned char* u8bufs[2] = { hu8A, hu8B };
    float* scbufs[2] = { scA, scB };
    for (int l = 1; l <= NLAY; l++) {
        const unsigned short* Mp = Mpack + (size_t)(l - 1) * 65536;
        if (l == NLAY) {
            k_layer<<<GB, 256, 0, stream>>>(rstart, counts, epack, hin, hinsc,
                                            h0u8, h0sc, Mp, nullptr, nullptr, hbf);
        } else {
            unsigned char* ou = u8bufs[(l - 1) & 1];
            float* os = scbufs[(l - 1) & 1];
            k_layer<<<GB, 256, 0, stream>>>(rstart, counts, epack, hin, hinsc,
                                            h0u8, h0sc, Mp, ou, os, nullptr);
            hin = ou; hinsc = os;
        }
    }

    // ---- logits + log_softmax (reads bf16 h, natural order)
    k_logits<<<(NNODES + 31) / 32, 256, 0, stream>>>(hbf, W1, b1, out, NNODES);
}

// Round 4
// 2191.632 us; speedup vs baseline: 1.3215x; 1.3215x over previous
//
#include <hip/hip_runtime.h>
#include <math.h>

// Problem constants (fixed by reference)
#define NNODES 100000
#define NEDGE  3200000
#define NF     512
#define NH     256
#define NC     40
#define NLAY   8
#define EPSV   1e-5f

// CSR bucket sort parameters
#define NBUK 782          // ceil(NNODES / 128); bucket = dst >> 7
#define EPB  16384        // edges per k_binA/k_histbuk block (1024 thr x 16)
#define BCAP 6144         // k_binB LDS capacity (avg bucket = 4096, sd ~64)

typedef __attribute__((ext_vector_type(8))) short short8;   // 8 bf16 (4 VGPRs)
typedef __attribute__((ext_vector_type(4))) float floatx4;  // MFMA acc

// Feature permutation (epilogue-natural uint8 store order):
//   pos(col) = (col&0xC0) | ((col&15)<<2) | ((col>>4)&3)
//   col(pos) = (pos&0xC0) | ((pos&3)<<4) | ((pos>>2)&15)
// All u8 h-buffers, sup, and Mpack k-rows live in pos space; layer-8 output and
// logits use natural order.
//
// NOTE (round-3 post-mortem): fusing spmm+gemm with a 35KB LDS sup tile dropped
// occupancy 66%->25% and cost +680us — the gather is LATENCY-bound and needs
// TLP, not traffic savings. Keep spmm/gemm split; optimize spmm VALU instead.

// ---------------------------------------------------------------- utilities

__device__ __forceinline__ float block_sum_256(float v) {
    __shared__ float sb[8];
    #pragma unroll
    for (int off = 32; off; off >>= 1) v += __shfl_down(v, off, 64);
    if ((threadIdx.x & 63) == 0) sb[threadIdx.x >> 6] = v;
    __syncthreads();
    return sb[0] + sb[1] + sb[2] + sb[3];
}

// round-to-nearest-even f32 -> bf16
__device__ __forceinline__ unsigned short bf16_rte(float a) {
    unsigned int u = __float_as_uint(a);
    return (unsigned short)((u + 0x7fffu + ((u >> 16) & 1u)) >> 16);
}
__device__ __forceinline__ unsigned int pack_bf2(float a, float b) {
    unsigned int ua = __float_as_uint(a), ub = __float_as_uint(b);
    ua = (ua + 0x7fffu + ((ua >> 16) & 1u)) >> 16;
    ub = (ub + 0x7fffu + ((ub >> 16) & 1u)) & 0xffff0000u;
    return ua | ub;
}

// ---------------------------------------------------------------- CSR build
// Bucket-only global hist (LDS-aggregated) + two-phase bucket sort. Per-node
// counts/rstart fall out of k_binB's LDS counting sort for free.

__global__ __launch_bounds__(1024) void k_histbuk(const int* __restrict__ dst,
                                                  int* __restrict__ bcnt) {
    __shared__ int lh[NBUK];
    const int t = threadIdx.x;
    if (t < NBUK) lh[t] = 0;
    __syncthreads();
    const int e0 = blockIdx.x * EPB;
    #pragma unroll
    for (int i = 0; i < 16; i++) {
        int e = e0 + i * 1024 + t;          // coalesced across the block
        if (e < NEDGE) atomicAdd(&lh[dst[e] >> 7], 1);
    }
    __syncthreads();
    if (t < NBUK) {
        int c = lh[t];
        if (c) atomicAdd(&bcnt[t], c);      // one global atomic per (block,bucket)
    }
}

// Single-block exclusive scan of 782 bucket counts -> bstart[0..NBUK]; init gcur.
__global__ __launch_bounds__(1024) void k_scanbuk(const int* __restrict__ bcnt,
                                                  int* __restrict__ bstart,
                                                  int* __restrict__ gcur) {
    __shared__ int s[1024];
    const int t = threadIdx.x;
    int v = (t < NBUK) ? bcnt[t] : 0;
    s[t] = v; __syncthreads();
    for (int off = 1; off < 1024; off <<= 1) {
        int u = (t >= off) ? s[t - off] : 0;
        __syncthreads();
        s[t] += u;
        __syncthreads();
    }
    if (t < NBUK) {
        int e = s[t] - v;                   // exclusive
        bstart[t] = e;
        gcur[t] = e;                        // stage cursor starts at bucket base
    }
    if (t == NBUK - 1) bstart[NBUK] = s[t]; // inclusive total == NEDGE
}

// Phase A: bin edges into 782 coarse buckets (128 dst-nodes each).
// One atomic reservation per (block,bucket); run writes stay XCD-local so L2
// merges them into full lines.
// Stage record: {pk = (src:17 | w_e8m7:15), dst_local (7 bits)}
__global__ __launch_bounds__(1024) void k_binA(const int* __restrict__ src,
                                               const int* __restrict__ dst,
                                               const float* __restrict__ w,
                                               int* __restrict__ gcur,
                                               uint2* __restrict__ gstage) {
    __shared__ int lhist[1024];        // per-bucket counts (782 used)
    __shared__ int lrun[NBUK];         // global run base per bucket
    __shared__ int lcnt[NBUK];         // local placement cursor
    const int t = threadIdx.x;
    lhist[t] = 0;
    if (t < NBUK) lcnt[t] = 0;
    __syncthreads();
    const int e0 = blockIdx.x * EPB;
    unsigned int pk[16]; int bk[16]; int dl[16];
    #pragma unroll
    for (int i = 0; i < 16; i++) {
        int e = e0 + i * 1024 + t;     // coalesced across the block
        bk[i] = -1;
        if (e < NEDGE) {
            int d = dst[e];
            bk[i] = d >> 7; dl[i] = d & 127;
            unsigned int wb = bf16_rte(w[e]) & 0x7FFFu;
            pk[i] = ((unsigned int)src[e] << 15) | wb;
            atomicAdd(&lhist[bk[i]], 1);
        }
    }
    __syncthreads();
    if (t < NBUK) {
        int c = lhist[t];
        if (c > 0) lrun[t] = atomicAdd(&gcur[t], c);   // one atomic per (block,bucket)
    }
    __syncthreads();
    #pragma unroll
    for (int i = 0; i < 16; i++) {
        if (bk[i] >= 0) {
            int p = lrun[bk[i]] + atomicAdd(&lcnt[bk[i]], 1);
            gstage[p] = make_uint2(pk[i], (unsigned int)dl[i]);
        }
    }
}

// Phase B: one block per bucket. LDS counting sort by dst_local (7 bits),
// then fully coalesced store of the final epack segment. Also emits per-node
// counts and rstart (free by-product of the LDS histogram + scan).
__global__ __launch_bounds__(256) void k_binB(const int* __restrict__ bstart,
                                              const uint2* __restrict__ gstage,
                                              unsigned int* __restrict__ epack,
                                              int* __restrict__ rstart,
                                              int* __restrict__ counts) {
    __shared__ unsigned int  spk[BCAP];
    __shared__ unsigned char sdl[BCAP];
    __shared__ unsigned int  lout[BCAP];
    __shared__ int lh[256];
    const int b = blockIdx.x, t = threadIdx.x;
    const int base = bstart[b];
    const int end  = bstart[b + 1];
    const int cnt = end - base;
    lh[t] = 0;
    __syncthreads();
    for (int i = t; i < cnt; i += 256) {
        uint2 e = gstage[base + i];
        spk[i] = e.x;
        int d = (int)(e.y & 127u);
        sdl[i] = (unsigned char)d;
        atomicAdd(&lh[d], 1);
    }
    __syncthreads();
    // exclusive scan over 256 slots (only 0..127 nonzero)
    int v = lh[t];
    for (int off = 1; off < 256; off <<= 1) {
        int u = (t >= off) ? lh[t - off] : 0;
        __syncthreads();
        lh[t] += u;
        __syncthreads();
    }
    int excl = lh[t] - v;
    __syncthreads();
    lh[t] = excl;                      // reuse as placement cursor
    // per-node CSR metadata (coalesced 512B per bucket)
    if (t < 128) {
        int node = (b << 7) + t;
        if (node < NNODES) { rstart[node] = base + excl; counts[node] = v; }
    }
    __syncthreads();
    for (int i = t; i < cnt; i += 256) {
        int p = atomicAdd(&lh[sdl[i]], 1);
        lout[p] = spk[i];
    }
    __syncthreads();
    for (int i = t; i < cnt; i += 256) epack[base + i] = lout[i];   // coalesced
}

// ---------------------------------------------------------------- x -> bf16 (coalesced)

__global__ void k_xbf16(const float* __restrict__ X, unsigned short* __restrict__ Xb, long n8) {
    long i = (long)blockIdx.x * 256 + threadIdx.x;   // one uint4 (8 bf16) per thread
    if (i >= n8) return;
    const float* p = X + i * 8;
    float4 a = *(const float4*)p;
    float4 b = *(const float4*)(p + 4);
    uint4 o;
    o.x = pack_bf2(a.x, a.y); o.y = pack_bf2(a.z, a.w);
    o.z = pack_bf2(b.x, b.y); o.w = pack_bf2(b.z, b.w);
    *(uint4*)(Xb + i * 8) = o;
}

// ---------------------------------------------------------------- ortho prep

__global__ void k_zc0(const float* __restrict__ W0, float* __restrict__ Zc0) {
    int r = blockIdx.x, t = threadIdx.x;
    float a = W0[r * NF + t];
    float b = W0[r * NF + 256 + t];
    float mean = block_sum_256(a + b) * (1.0f / 512.0f);
    Zc0[r * NF + t]       = a - mean;
    Zc0[r * NF + 256 + t] = b - mean;
}

__global__ void k_zcC(const float* __restrict__ convW, float* __restrict__ ZcC) {
    int g = blockIdx.x >> 8, r = blockIdx.x & 255, t = threadIdx.x;
    float v = 0.5f * convW[((size_t)g * NH + r) * NH + t] + ((r == t) ? 0.5f : 0.0f);
    float mean = block_sum_256(v) * (1.0f / 256.0f);
    ZcC[((size_t)g * NH + r) * NH + t] = v - mean;
}

// S[b] = Zc[b] @ Zc[b]^T + EPS*I   (b=0: Zc0 K=512; b>0: ZcC[b-1] K=256)
__global__ __launch_bounds__(256) void k_gram(const float* __restrict__ Zc0,
                                              const float* __restrict__ ZcC,
                                              float* __restrict__ S) {
    const int b = blockIdx.z;
    const float* A = (b == 0) ? Zc0 : (ZcC + (size_t)(b - 1) * 65536);
    const int K = (b == 0) ? 512 : 256;
    const int r0 = blockIdx.y * 64, c0 = blockIdx.x * 64;
    __shared__ float As[32][76], Bs[32][76];
    const int t = threadIdx.x, tx = t & 15, ty = t >> 4;
    const int lr = t >> 2, lk = (t & 3) * 4;
    float acc[4][4] = {};
    for (int k0 = 0; k0 < K; k0 += 32) {
        float4 a0 = *(const float4*)(A + (size_t)(r0 + lr) * K + k0 + lk);
        float4 a1 = *(const float4*)(A + (size_t)(r0 + lr) * K + k0 + lk + 16);
        As[lk + 0][lr] = a0.x; As[lk + 1][lr] = a0.y; As[lk + 2][lr] = a0.z; As[lk + 3][lr] = a0.w;
        As[lk + 16][lr] = a1.x; As[lk + 17][lr] = a1.y; As[lk + 18][lr] = a1.z; As[lk + 19][lr] = a1.w;
        float4 b0 = *(const float4*)(A + (size_t)(c0 + lr) * K + k0 + lk);
        float4 b1 = *(const float4*)(A + (size_t)(c0 + lr) * K + k0 + lk + 16);
        Bs[lk + 0][lr] = b0.x; Bs[lk + 1][lr] = b0.y; Bs[lk + 2][lr] = b0.z; Bs[lk + 3][lr] = b0.w;
        Bs[lk + 16][lr] = b1.x; Bs[lk + 17][lr] = b1.y; Bs[lk + 18][lr] = b1.z; Bs[lk + 19][lr] = b1.w;
        __syncthreads();
        #pragma unroll
        for (int kk = 0; kk < 32; kk++) {
            float a[4], bb[4];
            *(float4*)&a[0]  = *(const float4*)&As[kk][ty * 4];
            *(float4*)&bb[0] = *(const float4*)&Bs[kk][tx * 4];
            #pragma unroll
            for (int i = 0; i < 4; i++)
                #pragma unroll
                for (int j = 0; j < 4; j++) acc[i][j] = fmaf(a[i], bb[j], acc[i][j]);
        }
        __syncthreads();
    }
    #pragma unroll
    for (int i = 0; i < 4; i++)
        #pragma unroll
        for (int j = 0; j < 4; j++) {
            int r = r0 + ty * 4 + i, c = c0 + tx * 4 + j;
            float v = acc[i][j];
            if (r == c) v += EPSV;
            S[(size_t)b * 65536 + r * NH + c] = v;
        }
}

__global__ void k_fro(const float* __restrict__ S, float* __restrict__ scales) {
    __shared__ float sb[8];
    const int b = blockIdx.x, t = threadIdx.x;
    const float* p = S + (size_t)b * 65536;
    float s = 0.f;
    for (int i = t; i < 65536; i += 256) { float v = p[i]; s = fmaf(v, v, s); }
    #pragma unroll
    for (int off = 32; off; off >>= 1) s += __shfl_down(s, off, 64);
    if ((t & 63) == 0) sb[t >> 6] = s;
    __syncthreads();
    if (t == 0) {
        float nrm = sqrtf(sb[0] + sb[1] + sb[2] + sb[3]);
        scales[b]      = 1.0f / nrm;
        scales[16 + b] = rsqrtf(nrm);
    }
}

// B1 = 1.5*I - 0.5*invn*S  (closed-form first Newton-Schulz iteration)
__global__ void k_initB1(const float* __restrict__ S, const float* __restrict__ scales,
                         float* __restrict__ B) {
    int i = blockIdx.x * 256 + threadIdx.x;     // 9*65536
    int b = i >> 16, m = i & 65535;
    float v = -0.5f * scales[b] * S[i];
    if ((m >> 8) == (m & 255)) v += 1.5f;
    B[i] = v;
}

// Batch-18: b<9 -> T1[b] = B[b]@B[b] ; b>=9 -> T2[b-9] = B[b-9]@S[b-9]
__global__ __launch_bounds__(256) void k_ns_pair(const float* __restrict__ Bb,
                                                 const float* __restrict__ Smat,
                                                 float* __restrict__ T1b,
                                                 float* __restrict__ T2b) {
    const int b = blockIdx.z;
    const int bb = (b < 9) ? b : b - 9;
    const float* A  = Bb + (size_t)bb * 65536;
    const float* Bm = (b < 9) ? A : (Smat + (size_t)bb * 65536);
    float* C = (b < 9) ? (T1b + (size_t)bb * 65536) : (T2b + (size_t)bb * 65536);
    const int r0 = blockIdx.y * 64, c0 = blockIdx.x * 64;
    __shared__ float As[32][76], Bs[32][76];
    const int t = threadIdx.x, tx = t & 15, ty = t >> 4;
    const int lr = t >> 2, lk = (t & 3) * 4;
    const int bk = t >> 3, bc = (t & 7) * 8;
    float acc[4][4] = {};
    for (int k0 = 0; k0 < 256; k0 += 32) {
        float4 a0 = *(const float4*)(A + (size_t)(r0 + lr) * 256 + k0 + lk);
        float4 a1 = *(const float4*)(A + (size_t)(r0 + lr) * 256 + k0 + lk + 16);
        As[lk + 0][lr] = a0.x; As[lk + 1][lr] = a0.y; As[lk + 2][lr] = a0.z; As[lk + 3][lr] = a0.w;
        As[lk + 16][lr] = a1.x; As[lk + 17][lr] = a1.y; As[lk + 18][lr] = a1.z; As[lk + 19][lr] = a1.w;
        float4 b0 = *(const float4*)(Bm + (size_t)(k0 + bk) * 256 + c0 + bc);
        float4 b1 = *(const float4*)(Bm + (size_t)(k0 + bk) * 256 + c0 + bc + 4);
        *(float4*)&Bs[bk][bc]     = b0;
        *(float4*)&Bs[bk][bc + 4] = b1;
        __syncthreads();
        #pragma unroll
        for (int kk = 0; kk < 32; kk++) {
            float a[4], bb2[4];
            *(float4*)&a[0]   = *(const float4*)&As[kk][ty * 4];
            *(float4*)&bb2[0] = *(const float4*)&Bs[kk][tx * 4];
            #pragma unroll
            for (int i = 0; i < 4; i++)
                #pragma unroll
                for (int j = 0; j < 4; j++) acc[i][j] = fmaf(a[i], bb2[j], acc[i][j]);
        }
        __syncthreads();
    }
    #pragma unroll
    for (int i = 0; i < 4; i++)
        #pragma unroll
        for (int j = 0; j < 4; j++)
            C[(size_t)(r0 + ty * 4 + i) * 256 + c0 + tx * 4 + j] = acc[i][j];
}

// Batched small NN matmul, M=256, tile 64x64, Ktile 32.
// mode 1: C = 1.5*C - 0.5*scale[b]*(A@B) ; mode 2: C = scale[b]*(A@B)
__global__ __launch_bounds__(256) void k_small_nn(const float* __restrict__ A0,
                                                  const float* __restrict__ B0,
                                                  float* __restrict__ C0,
                                                  int sA, int sB, int sC,
                                                  int K, int Ncols, int mode,
                                                  const float* __restrict__ scale) {
    const int b = blockIdx.z;
    const float* A = A0 + (size_t)b * sA;
    const float* Bm = B0 + (size_t)b * sB;
    float* C = C0 + (size_t)b * sC;
    const int r0 = blockIdx.y * 64, c0 = blockIdx.x * 64;
    __shared__ float As[32][76], Bs[32][76];
    const int t = threadIdx.x, tx = t & 15, ty = t >> 4;
    const int lr = t >> 2, lk = (t & 3) * 4;
    const int bk = t >> 3, bc = (t & 7) * 8;
    float acc[4][4] = {};
    for (int k0 = 0; k0 < K; k0 += 32) {
        float4 a0 = *(const float4*)(A + (size_t)(r0 + lr) * K + k0 + lk);
        float4 a1 = *(const float4*)(A + (size_t)(r0 + lr) * K + k0 + lk + 16);
        As[lk + 0][lr] = a0.x; As[lk + 1][lr] = a0.y; As[lk + 2][lr] = a0.z; As[lk + 3][lr] = a0.w;
        As[lk + 16][lr] = a1.x; As[lk + 17][lr] = a1.y; As[lk + 18][lr] = a1.z; As[lk + 19][lr] = a1.w;
        float4 b0 = *(const float4*)(Bm + (size_t)(k0 + bk) * Ncols + c0 + bc);
        float4 b1 = *(const float4*)(Bm + (size_t)(k0 + bk) * Ncols + c0 + bc + 4);
        *(float4*)&Bs[bk][bc]     = b0;
        *(float4*)&Bs[bk][bc + 4] = b1;
        __syncthreads();
        #pragma unroll
        for (int kk = 0; kk < 32; kk++) {
            float a[4], bb[4];
            *(float4*)&a[0]  = *(const float4*)&As[kk][ty * 4];
            *(float4*)&bb[0] = *(const float4*)&Bs[kk][tx * 4];
            #pragma unroll
            for (int i = 0; i < 4; i++)
                #pragma unroll
                for (int j = 0; j < 4; j++) acc[i][j] = fmaf(a[i], bb[j], acc[i][j]);
        }
        __syncthreads();
    }
    #pragma unroll
    for (int i = 0; i < 4; i++)
        #pragma unroll
        for (int j = 0; j < 4; j++) {
            size_t idx = (size_t)(r0 + ty * 4 + i) * Ncols + c0 + tx * 4 + j;
            if (mode == 1) C[idx] = 1.5f * C[idx] - 0.5f * scale[b] * acc[i][j];
            else C[idx] = scale[b] * acc[i][j];
        }
}

// ---------------------------------------------------------------- MFMA B-operand packing
// Fragment layouts (gfx950 mfma_f32_16x16x32_bf16):
//   A: lane holds A[m=lane&15][k=(lane>>4)*8 + j], j=0..7
//   B: lane holds B[k=(lane>>4)*8 + j][n=lane&15]
//   C/D: col=lane&15, row=(lane>>4)*4 + reg
// Pack layout: [c=K/64][s=2][tg=16][lane=64][j=8] bf16 (per-chunk 32 KB contiguous)

// Mpack k-index is in pos space: Mpack[k_pos][n] = M[col(k_pos)][n]
__global__ void k_prepM(const float* __restrict__ tbuf, unsigned short* __restrict__ Mpack) {
    int idx = blockIdx.x * 256 + threadIdx.x;
    int lane = idx & 63;
    int tg   = (idx >> 6) & 15;
    int s    = (idx >> 10) & 1;
    int c    = (idx >> 11) & 3;
    int l    = idx >> 13;
    float theta = logf(0.5f / (float)(l + 1) + 1.0f);
    float mtheta = 1.0f - theta;
    int n  = tg * 16 + (lane & 15);
    int k0 = c * 64 + s * 32 + (lane >> 4) * 8;
    const float* T = tbuf + (size_t)l * 65536;
    unsigned short o[8];
    #pragma unroll
    for (int j = 0; j < 8; j++) {
        int kp = k0 + j;
        int kn = (kp & 0xC0) | ((kp & 3) << 4) | ((kp >> 2) & 15);   // col(pos)
        float v = theta * T[(size_t)kn * 256 + n] + ((kn == n) ? mtheta : 0.0f);
        o[j] = bf16_rte(v);
    }
    *(uint4*)(Mpack + (size_t)idx * 8) = *(uint4*)o;
}

// fc0 k-space = x features (natural, no perm)
__global__ void k_prepW0(const float* __restrict__ W0o, unsigned short* __restrict__ Wpack) {
    int idx = blockIdx.x * 256 + threadIdx.x;
    int lane = idx & 63;
    int tg   = (idx >> 6) & 15;
    int s    = (idx >> 10) & 1;
    int c    = idx >> 11;                    // 0..7
    int n  = tg * 16 + (lane & 15);
    int k0 = c * 64 + s * 32 + (lane >> 4) * 8;
    const float* p = W0o + (size_t)n * NF + k0;
    unsigned short o[8];
    #pragma unroll
    for (int j = 0; j < 8; j++) o[j] = bf16_rte(p[j]);
    *(uint4*)(Wpack + (size_t)idx * 8) = *(uint4*)o;
}

// ---------------------------------------------------------------- fc0 (MFMA, LDS-free)

// h0u8/h0scale = quant(relu(xbf @ W0o^T + b0)). K=512 (8 chunks).
__global__ __launch_bounds__(256) void k_fc0_mfma(const unsigned short* __restrict__ Xb,
                                                  const unsigned short* __restrict__ Wp,
                                                  const float* __restrict__ bias,
                                                  unsigned char* __restrict__ h0u8,
                                                  float* __restrict__ h0scale) {
    __shared__ int rmax[64];
    const int t = threadIdx.x, lane = t & 63, w = t >> 6;
    const int q = lane >> 4, m = lane & 15;
    const int r0 = blockIdx.x * 64;
    if (t < 64) rmax[t] = 0;
    floatx4 acc[4][4] = {};
    #pragma unroll
    for (int c = 0; c < 8; c++) {
        #pragma unroll
        for (int s = 0; s < 2; s++) {
            short8 afr[4];
            #pragma unroll
            for (int i = 0; i < 4; i++) {
                int row = r0 + i * 16 + m; if (row > NNODES - 1) row = NNODES - 1;
                afr[i] = *(const short8*)(Xb + (size_t)row * NF + c * 64 + s * 32 + q * 8);
            }
            #pragma unroll
            for (int tg = 0; tg < 4; tg++) {
                short8 bfr = *(const short8*)(Wp + (size_t)c * 16384 + s * 8192
                                              + (w * 4 + tg) * 512 + lane * 8);
                #pragma unroll
                for (int i = 0; i < 4; i++)
                    acc[i][tg] = __builtin_amdgcn_mfma_f32_16x16x32_bf16(afr[i], bfr, acc[i][tg], 0, 0, 0);
            }
        }
    }
    // bias + relu in place
    #pragma unroll
    for (int tg = 0; tg < 4; tg++) {
        float bv = bias[w * 64 + tg * 16 + m];
        #pragma unroll
        for (int i = 0; i < 4; i++)
            #pragma unroll
            for (int r = 0; r < 4; r++)
                acc[i][tg][r] = fmaxf(acc[i][tg][r] + bv, 0.f);
    }
    __syncthreads();   // rmax init visible
    // row max (phase A)
    #pragma unroll
    for (int i = 0; i < 4; i++)
        #pragma unroll
        for (int r = 0; r < 4; r++) {
            float mx = fmaxf(fmaxf(acc[i][0][r], acc[i][1][r]),
                             fmaxf(acc[i][2][r], acc[i][3][r]));
            mx = fmaxf(mx, __shfl_xor(mx, 1));
            mx = fmaxf(mx, __shfl_xor(mx, 2));
            mx = fmaxf(mx, __shfl_xor(mx, 4));
            mx = fmaxf(mx, __shfl_xor(mx, 8));
            if (m == 0) atomicMax(&rmax[i * 16 + q * 4 + r], __float_as_int(mx));
        }
    __syncthreads();
    // quantize + store (phase B)
    #pragma unroll
    for (int i = 0; i < 4; i++)
        #pragma unroll
        for (int r = 0; r < 4; r++) {
            int row = r0 + i * 16 + q * 4 + r;
            if (row >= NNODES) continue;
            float rm = __int_as_float(rmax[i * 16 + q * 4 + r]);
            float qs = rm > 0.f ? 255.0f / rm : 0.f;
            unsigned int b0 = (unsigned int)fmaf(acc[i][0][r], qs, 0.5f);
            unsigned int b1 = (unsigned int)fmaf(acc[i][1][r], qs, 0.5f);
            unsigned int b2 = (unsigned int)fmaf(acc[i][2][r], qs, 0.5f);
            unsigned int b3 = (unsigned int)fmaf(acc[i][3][r], qs, 0.5f);
            *(unsigned int*)(h0u8 + (size_t)row * NH + w * 64 + m * 4) =
                b0 | (b1 << 8) | (b2 << 16) | (b3 << 24);
        }
    if (t < 64 && r0 + t < NNODES)
        h0scale[r0 + t] = __int_as_float(rmax[t]) * (1.0f / 255.0f);
}

// ---------------------------------------------------------------- SpMM (uint8 gather)

// One wave per dst node; lane owns 4 pos-features (4B gather per lane).
// supbf[d,:] = bf16( 0.9*sum_e w_e*h[src_e,:] + 0.1*h0[d,:] ), h/h0 uint8+rowscale.
// se.x holds src<<8 so the inner-loop gather offset is a single 32-bit v_or
// (ed.x | lane*4) feeding the saddr global_load form — the old
// (size_t)src<<8 64-bit chain was ~4 extra VALU per edge (30% of edge cost).
__global__ __launch_bounds__(256) void k_spmm(const int* __restrict__ rstart,
                                              const int* __restrict__ counts,
                                              const unsigned int* __restrict__ epack,
                                              const unsigned char* __restrict__ hu8,
                                              const float* __restrict__ hscale,
                                              const unsigned char* __restrict__ h0u8,
                                              const float* __restrict__ h0scale,
                                              unsigned short* __restrict__ supbf) {
    __shared__ uint2 se[4][64];
    const int wv = threadIdx.x >> 6, lane = threadIdx.x & 63;
    const unsigned int lo4 = (unsigned int)(lane << 2);
    const int node = blockIdx.x * 4 + wv;
    const int start = rstart[node], deg = counts[node];
    float a0 = 0.f, a1 = 0.f, a2 = 0.f, a3 = 0.f;
    for (int base = 0; base < deg; base += 64) {
        int j = base + lane;
        if (j < deg) {
            unsigned int u = epack[start + j];
            unsigned int s = u >> 15;
            float wt = __uint_as_float((u & 0x7FFFu) << 16);   // e8m7, sign 0
            se[wv][lane] = make_uint2(s << 8, __float_as_uint(wt * hscale[s] * 0.9f));
        }
        int mm = deg - base; if (mm > 64) mm = 64;
        int e = 0;
        for (; e + 8 <= mm; e += 8) {
            float ww[8]; unsigned int g[8];
            #pragma unroll
            for (int u2 = 0; u2 < 8; u2++) {
                uint2 ed = se[wv][e + u2];
                ww[u2] = __uint_as_float(ed.y);
                g[u2] = *(const unsigned int*)(hu8 + (ed.x | lo4));
            }
            #pragma unroll
            for (int u2 = 0; u2 < 8; u2++) {
                a0 = fmaf(ww[u2], (float)(g[u2] & 0xFFu), a0);
                a1 = fmaf(ww[u2], (float)((g[u2] >> 8) & 0xFFu), a1);
                a2 = fmaf(ww[u2], (float)((g[u2] >> 16) & 0xFFu), a2);
                a3 = fmaf(ww[u2], (float)(g[u2] >> 24), a3);
            }
        }
        for (; e < mm; e++) {
            uint2 ed = se[wv][e];
            float ww = __uint_as_float(ed.y);
            unsigned int g = *(const unsigned int*)(hu8 + (ed.x | lo4));
            a0 = fmaf(ww, (float)(g & 0xFFu), a0);
            a1 = fmaf(ww, (float)((g >> 8) & 0xFFu), a1);
            a2 = fmaf(ww, (float)((g >> 16) & 0xFFu), a2);
            a3 = fmaf(ww, (float)(g >> 24), a3);
        }
    }
    unsigned int rg = *(const unsigned int*)(h0u8 + (((unsigned int)node << 8) | lo4));
    float rs = h0scale[node] * 0.1f;
    float o0 = fmaf(rs, (float)(rg & 0xFFu), a0);
    float o1 = fmaf(rs, (float)((rg >> 8) & 0xFFu), a1);
    float o2 = fmaf(rs, (float)((rg >> 16) & 0xFFu), a2);
    float o3 = fmaf(rs, (float)(rg >> 24), a3);
    uint2 ov;
    ov.x = pack_bf2(o0, o1);
    ov.y = pack_bf2(o2, o3);
    *(uint2*)(supbf + ((size_t)node << 8) + (lane << 2)) = ov;
}

// ---------------------------------------------------------------- layer GEMM (MFMA, no LDS staging)

// D = relu(Sbf @ M). l=1..7: quantize rows to uint8+scale (pos space).
// l=8 (out_bf != null): bf16 natural store for logits.
__global__ __launch_bounds__(256) void k_gemm_layer(const unsigned short* __restrict__ Sbf,
                                                    const unsigned short* __restrict__ Mp,
                                                    unsigned char* __restrict__ out_u8,
                                                    float* __restrict__ out_scale,
                                                    unsigned short* __restrict__ out_bf) {
    __shared__ int rmax[64];
    const int t = threadIdx.x, lane = t & 63, w = t >> 6;
    const int q = lane >> 4, m = lane & 15;
    const int r0 = blockIdx.x * 64;
    if (t < 64) rmax[t] = 0;
    floatx4 acc[4][4] = {};
    #pragma unroll
    for (int c = 0; c < 4; c++) {
        #pragma unroll
        for (int s = 0; s < 2; s++) {
            short8 afr[4];
            #pragma unroll
            for (int i = 0; i < 4; i++) {
                int row = r0 + i * 16 + m; if (row > NNODES - 1) row = NNODES - 1;
                afr[i] = *(const short8*)(Sbf + (size_t)row * NH + c * 64 + s * 32 + q * 8);
            }
            #pragma unroll
            for (int tg = 0; tg < 4; tg++) {
                short8 bfr = *(const short8*)(Mp + (size_t)c * 16384 + s * 8192
                                              + (w * 4 + tg) * 512 + lane * 8);
                #pragma unroll
                for (int i = 0; i < 4; i++)
                    acc[i][tg] = __builtin_amdgcn_mfma_f32_16x16x32_bf16(afr[i], bfr, acc[i][tg], 0, 0, 0);
            }
        }
    }
    // relu in place
    #pragma unroll
    for (int i = 0; i < 4; i++)
        #pragma unroll
        for (int tg = 0; tg < 4; tg++)
            #pragma unroll
            for (int r = 0; r < 4; r++)
                acc[i][tg][r] = fmaxf(acc[i][tg][r], 0.f);

    if (out_bf) {   // layer 8: natural bf16 scatter
        #pragma unroll
        for (int i = 0; i < 4; i++)
            #pragma unroll
            for (int tg = 0; tg < 4; tg++) {
                int col = w * 64 + tg * 16 + m;
                #pragma unroll
                for (int r = 0; r < 4; r++) {
                    int row = r0 + i * 16 + q * 4 + r;
                    if (row >= NNODES) continue;
                    out_bf[(size_t)row * NH + col] = bf16_rte(acc[i][tg][r]);
                }
            }
        return;
    }
    // phase A: row max
    __syncthreads();   // rmax init visible
    #pragma unroll
    for (int i = 0; i < 4; i++)
        #pragma unroll
        for (int r = 0; r < 4; r++) {
            float mx = fmaxf(fmaxf(acc[i][0][r], acc[i][1][r]),
                             fmaxf(acc[i][2][r], acc[i][3][r]));
            mx = fmaxf(mx, __shfl_xor(mx, 1));
            mx = fmaxf(mx, __shfl_xor(mx, 2));
            mx = fmaxf(mx, __shfl_xor(mx, 4));
            mx = fmaxf(mx, __shfl_xor(mx, 8));
            if (m == 0) atomicMax(&rmax[i * 16 + q * 4 + r], __float_as_int(mx));
        }
    __syncthreads();
    // phase B: quantize + pos-space dword stores
    #pragma unroll
    for (int i = 0; i < 4; i++)
        #pragma unroll
        for (int r = 0; r < 4; r++) {
            int row = r0 + i * 16 + q * 4 + r;
            if (row >= NNODES) continue;
            float rm = __int_as_float(rmax[i * 16 + q * 4 + r]);
            float qs = rm > 0.f ? 255.0f / rm : 0.f;
            unsigned int b0 = (unsigned int)fmaf(acc[i][0][r], qs, 0.5f);
            unsigned int b1 = (unsigned int)fmaf(acc[i][1][r], qs, 0.5f);
            unsigned int b2 = (unsigned int)fmaf(acc[i][2][r], qs, 0.5f);
            unsigned int b3 = (unsigned int)fmaf(acc[i][3][r], qs, 0.5f);
            *(unsigned int*)(out_u8 + (size_t)row * NH + w * 64 + m * 4) =
                b0 | (b1 << 8) | (b2 << 16) | (b3 << 24);
        }
    if (t < 64 && r0 + t < NNODES)
        out_scale[r0 + t] = __int_as_float(rmax[t]) * (1.0f / 255.0f);
}

// ---------------------------------------------------------------- logits + log_softmax (bf16 h, natural)

__global__ __launch_bounds__(256) void k_logits(const unsigned short* __restrict__ hb,
                                                const float* __restrict__ W1,
                                                const float* __restrict__ b1,
                                                float* __restrict__ out, int nrows) {
    __shared__ float hs[32][260];
    __shared__ float Ws[40][260];
    __shared__ float ls[32][44];
    __shared__ float lse[32];
    const int t = threadIdx.x;
    const int row0 = blockIdx.x * 32;
    for (int i = t; i < 40 * 64; i += 256) {
        int c = i >> 6, k4 = i & 63;
        *(float4*)&Ws[c][k4 * 4] = *(const float4*)(W1 + (size_t)c * NH + k4 * 4);
    }
    for (int i = t; i < 32 * 32; i += 256) {
        int r = i >> 5, k8 = i & 31;
        int gr = row0 + r;
        uint4 v = make_uint4(0u, 0u, 0u, 0u);
        if (gr < nrows) v = *(const uint4*)(hb + ((size_t)gr << 8) + k8 * 8);
        float* d = &hs[r][k8 * 8];
        d[0] = __uint_as_float(v.x << 16); d[1] = __uint_as_float(v.x & 0xffff0000u);
        d[2] = __uint_as_float(v.y << 16); d[3] = __uint_as_float(v.y & 0xffff0000u);
        d[4] = __uint_as_float(v.z << 16); d[5] = __uint_as_float(v.z & 0xffff0000u);
        d[6] = __uint_as_float(v.w << 16); d[7] = __uint_as_float(v.w & 0xffff0000u);
    }
    __syncthreads();
    const int r = t & 31, cg = t >> 5;   // cg in 0..7, 5 classes each
    float acc[5];
    #pragma unroll
    for (int j = 0; j < 5; j++) acc[j] = b1[cg * 5 + j];
    for (int k = 0; k < NH; k++) {
        float hv = hs[r][k];
        #pragma unroll
        for (int j = 0; j < 5; j++) acc[j] = fmaf(hv, Ws[cg * 5 + j][k], acc[j]);
    }
    #pragma unroll
    for (int j = 0; j < 5; j++) ls[r][cg * 5 + j] = acc[j];
    __syncthreads();
    if (t < 32) {
        float m = -3.4e38f;
        for (int c = 0; c < NC; c++) m = fmaxf(m, ls[t][c]);
        float s = 0.f;
        for (int c = 0; c < NC; c++) s += expf(ls[t][c] - m);
        lse[t] = m + logf(s);
    }
    __syncthreads();
    for (int i = t; i < 32 * NC; i += 256) {
        int r2 = i / NC, c = i % NC;
        int gr = row0 + r2;
        if (gr < nrows) out[(size_t)gr * NC + c] = ls[r2][c] - lse[r2];
    }
}

// ---------------------------------------------------------------- launch

extern "C" void kernel_launch(void* const* d_in, const int* in_sizes, int n_in,
                              void* d_out, int out_size, void* d_ws, size_t ws_size,
                              hipStream_t stream) {
    const float* x      = (const float*)d_in[0];
    const int*   e_src  = (const int*)d_in[1];
    const int*   e_dst  = (const int*)d_in[2];
    const float* e_w    = (const float*)d_in[3];
    const float* W0     = (const float*)d_in[4];
    const float* b0     = (const float*)d_in[5];
    const float* convW  = (const float*)d_in[6];
    const float* W1     = (const float*)d_in[7];
    const float* b1     = (const float*)d_in[8];
    float* out = (float*)d_out;

    char* ws = (char*)d_ws;
    const size_t OFF_H0U8   = 0;                                    // u8 [N,256] 25.6 MB
    const size_t OFF_HU8A   = OFF_H0U8 + (size_t)NNODES * NH;       // u8 [N,256]
    const size_t OFF_HU8B   = OFF_HU8A + (size_t)NNODES * NH;       // u8 [N,256]
    const size_t OFF_H0SC   = OFF_HU8B + (size_t)NNODES * NH;       // f32 [N]
    const size_t OFF_SCA    = OFF_H0SC + (size_t)NNODES * 4;
    const size_t OFF_SCB    = OFF_SCA + (size_t)NNODES * 4;
    const size_t OFF_SUPBF  = OFF_SCB + (size_t)NNODES * 4;         // bf16 [N,256] 51.2 MB (aliased: gstage during CSR build)
    const size_t OFF_HBF    = OFF_SUPBF + (size_t)NNODES * NH * 2;  // bf16 [N,256] (layer-8)
    const size_t OFF_XBF    = OFF_HBF + (size_t)NNODES * NH * 2;    // bf16 [N,512] 102.4 MB
    const size_t OFF_EPACK  = OFF_XBF + (size_t)NNODES * NF * 2;    // u32 [E] 12.8 MB
    const size_t OFF_RSTART = OFF_EPACK + (size_t)NEDGE * 4;
    const size_t OFF_COUNTS = OFF_RSTART + (size_t)NNODES * 4;
    const size_t OFF_CURSOR = OFF_COUNTS + (size_t)NNODES * 4;      // gcur (782) + bcnt + bstart
    const size_t OFF_BSUM   = OFF_CURSOR + (size_t)NNODES * 4;
    const size_t OFF_ZC0    = OFF_BSUM + 1024;
    const size_t OFF_ZCC    = OFF_ZC0 + 256 * 512 * 4;
    const size_t OFF_S      = OFF_ZCC + 8 * 65536 * 4;
    const size_t OFF_B      = OFF_S + 9 * 65536 * 4;
    const size_t OFF_T1     = OFF_B + 9 * 65536 * 4;
    const size_t OFF_T2     = OFF_T1 + 9 * 65536 * 4;
    const size_t OFF_T      = OFF_T2 + 9 * 65536 * 4;
    const size_t OFF_W0O    = OFF_T + 8 * 65536 * 4;
    const size_t OFF_SCALES = OFF_W0O + 256 * 512 * 4;
    const size_t OFF_MPACK  = OFF_SCALES + 1024;
    const size_t OFF_WPACK  = OFF_MPACK + 8 * 65536 * 2;

    unsigned char* h0u8 = (unsigned char*)(ws + OFF_H0U8);
    unsigned char* hu8A = (unsigned char*)(ws + OFF_HU8A);
    unsigned char* hu8B = (unsigned char*)(ws + OFF_HU8B);
    float* h0sc = (float*)(ws + OFF_H0SC);
    float* scA  = (float*)(ws + OFF_SCA);
    float* scB  = (float*)(ws + OFF_SCB);
    unsigned short* supbf = (unsigned short*)(ws + OFF_SUPBF);
    unsigned short* hbf   = (unsigned short*)(ws + OFF_HBF);
    unsigned short* xbf   = (unsigned short*)(ws + OFF_XBF);
    unsigned int* epack  = (unsigned int*)(ws + OFF_EPACK);
    int*    rstart = (int*)(ws + OFF_RSTART);
    int*    counts = (int*)(ws + OFF_COUNTS);
    int*    gcur   = (int*)(ws + OFF_CURSOR);
    int*    bcnt   = (int*)(ws + OFF_CURSOR + 4096);
    int*    bstart = (int*)(ws + OFF_CURSOR + 8192);                // NBUK+1 ints
    float*  Zc0    = (float*)(ws + OFF_ZC0);
    float*  ZcC    = (float*)(ws + OFF_ZCC);
    float*  Smat   = (float*)(ws + OFF_S);
    float*  Bb     = (float*)(ws + OFF_B);
    float*  T1b    = (float*)(ws + OFF_T1);
    float*  T2b    = (float*)(ws + OFF_T2);
    float*  tbuf   = (float*)(ws + OFF_T);
    float*  W0o    = (float*)(ws + OFF_W0O);
    float*  scales = (float*)(ws + OFF_SCALES);
    unsigned short* Mpack = (unsigned short*)(ws + OFF_MPACK);
    unsigned short* Wpack = (unsigned short*)(ws + OFF_WPACK);
    uint2* gstage = (uint2*)(ws + OFF_SUPBF);   // 25.6 MB alias; dead until first k_spmm

    (void)in_sizes; (void)n_in; (void)out_size; (void)ws_size;

    // ---- CSR build (bucket-only global hist, then two-phase bucket sort)
    hipMemsetAsync(bcnt, 0, (size_t)NBUK * 4, stream);
    const int NBA = (NEDGE + EPB - 1) / EPB;   // 196
    k_histbuk<<<NBA, 1024, 0, stream>>>(e_dst, bcnt);
    k_scanbuk<<<1, 1024, 0, stream>>>(bcnt, bstart, gcur);
    k_binA<<<NBA, 1024, 0, stream>>>(e_src, e_dst, e_w, gcur, gstage);
    k_binB<<<NBUK, 256, 0, stream>>>(bstart, gstage, epack, rstart, counts);

    // ---- x -> bf16 (coalesced one-shot)
    const long N8 = (long)NNODES * NF / 8;   // 6,400,000
    k_xbf16<<<(int)((N8 + 255) / 256), 256, 0, stream>>>(x, xbf, N8);

    // ---- ortho: batched Newton-Schulz (T=5; first iteration closed-form)
    k_zc0<<<256, 256, 0, stream>>>(W0, Zc0);
    k_zcC<<<8 * 256, 256, 0, stream>>>(convW, ZcC);
    k_gram<<<dim3(4, 4, 9), 256, 0, stream>>>(Zc0, ZcC, Smat);
    k_fro<<<9, 256, 0, stream>>>(Smat, scales);
    k_initB1<<<9 * 256, 256, 0, stream>>>(Smat, scales, Bb);
    for (int it = 1; it < 5; it++) {
        k_ns_pair<<<dim3(4, 4, 18), 256, 0, stream>>>(Bb, Smat, T1b, T2b);
        k_small_nn<<<dim3(4, 4, 9), 256, 0, stream>>>(T1b, T2b, Bb, 65536, 65536, 65536,
                                                      256, 256, 1, scales);
    }
    // W0o = (B0 @ Zc0) * rsqn[0]; t[g] = (B[g+1] @ ZcC[g]) * rsqn[g+1]
    k_small_nn<<<dim3(8, 4, 1), 256, 0, stream>>>(Bb, Zc0, W0o, 0, 0, 0,
                                                  256, 512, 2, scales + 16);
    k_small_nn<<<dim3(4, 4, 8), 256, 0, stream>>>(Bb + 65536, ZcC, tbuf, 65536, 65536, 65536,
                                                  256, 256, 2, scales + 17);

    // ---- pack B-operands for MFMA
    k_prepM<<<256, 256, 0, stream>>>(tbuf, Mpack);
    k_prepW0<<<64, 256, 0, stream>>>(W0o, Wpack);

    // ---- fc0 (MFMA, LDS-free): h0u8/h0sc = quant(relu(xbf @ W0o^T + b0))
    const int GB = (NNODES + 63) / 64;   // 1563
    k_fc0_mfma<<<GB, 256, 0, stream>>>(xbf, Wpack, b0, h0u8, h0sc);

    // ---- 8 GCNII layers: u8 gather spmm -> bf16 sup -> MFMA GEMM -> u8 (or bf16 l=8)
    const unsigned char* hin = h0u8;
    const float* hinsc = h0sc;
    unsigned char* u8bufs[2] = { hu8A, hu8B };
    float* scbufs[2] = { scA, scB };
    for (int l = 1; l <= NLAY; l++) {
        k_spmm<<<NNODES / 4, 256, 0, stream>>>(rstart, counts, epack, hin, hinsc,
                                               h0u8, h0sc, supbf);
        const unsigned short* Mp = Mpack + (size_t)(l - 1) * 65536;
        if (l == NLAY) {
            k_gemm_layer<<<GB, 256, 0, stream>>>(supbf, Mp, nullptr, nullptr, hbf);
        } else {
            unsigned char* ou = u8bufs[(l - 1) & 1];
            float* os = scbufs[(l - 1) & 1];
            k_gemm_layer<<<GB, 256, 0, stream>>>(supbf, Mp, ou, os, nullptr);
            hin = ou; hinsc = os;
        }
    }

    // ---- logits + log_softmax (reads bf16 h, natural order)
    k_logits<<<(NNODES + 31) / 32, 256, 0, stream>>>(hbf, W1, b1, out, NNODES);
}